// Round 1
// baseline (5844.489 us; speedup 1.0000x reference)
//
#include <hip/hip_runtime.h>
#include <math.h>

#define N_NODES 40000
#define N_EDGES 512000
#define SDIM 128
#define EDIM 128
#define HID 64
#define DEPTH 4
#define MSG_IN 386   // 2*SDIM + EDIM + 2
#define SCAL_IN 192  // SDIM + HID
#define CUTOFF 5.0f
#define EPS_D 1e-6f

__device__ __forceinline__ float silu_f(float x) { return x / (1.0f + __expf(-x)); }

__global__ __launch_bounds__(256) void k_zero(float* __restrict__ p, int n) {
  int i = blockIdx.x * 256 + threadIdx.x;
  int stride = gridDim.x * 256;
  for (; i < n; i += stride) p[i] = 0.0f;
}

__global__ __launch_bounds__(256) void k_deg_count(const int* __restrict__ dst,
                                                   float* __restrict__ deg, int ne) {
  int i = blockIdx.x * 256 + threadIdx.x;
  if (i < ne) atomicAdd(&deg[dst[i]], 1.0f);
}

__global__ __launch_bounds__(256) void k_deg_inv(float* __restrict__ deg, int n) {
  int i = blockIdx.x * 256 + threadIdx.x;
  if (i < n) deg[i] = 1.0f / fmaxf(deg[i], 1.0f);
}

// Sa = s @ We1[rows 0:128] + be1 ; Sb = s @ We1[rows 128:256]
// one wave per node, lane j owns output column j
__global__ __launch_bounds__(256) void k_node_pre(
    const float* __restrict__ s, const float* __restrict__ W1,
    const float* __restrict__ be1_, float* __restrict__ Sa, float* __restrict__ Sb) {
  __shared__ float s_lds[4][SDIM];
  const int wave = threadIdx.x >> 6, lane = threadIdx.x & 63;
  const int node = blockIdx.x * 4 + wave;   // N divisible by 4
  const float2 s2 = reinterpret_cast<const float2*>(s + (size_t)node * SDIM)[lane];
  reinterpret_cast<float2*>(s_lds[wave])[lane] = s2;
  __syncthreads();
  float a = be1_[lane], b = 0.0f;
#pragma unroll 8
  for (int k = 0; k < SDIM; ++k) {
    const float sk = s_lds[wave][k];
    a += sk * W1[k * HID + lane];
    b += sk * W1[(SDIM + k) * HID + lane];
  }
  Sa[(size_t)node * HID + lane] = a;
  Sb[(size_t)node * HID + lane] = b;
}

// one wave per edge
__global__ __launch_bounds__(256) void k_edge(
    const float* __restrict__ e_src_buf, float* __restrict__ e_dst_buf,
    const float* __restrict__ vbuf,
    const float* __restrict__ Sa, const float* __restrict__ Sb,
    const int* __restrict__ srcs, const int* __restrict__ dsts,
    const float* __restrict__ ead,
    const float* __restrict__ W1e,  // rows 256..383 of We1[i] : [128][64]
    const float* __restrict__ w1d,  // row 384
    const float* __restrict__ w1a,  // row 385
    const float* __restrict__ We2_, const float* __restrict__ be2_,
    const float* __restrict__ Weo_, const float* __restrict__ beo_,
    const float* __restrict__ Wv_, const float* __restrict__ bv_,
    float* __restrict__ v_acc, float* __restrict__ agg) {
  __shared__ float e_lds[4][EDIM];
  __shared__ float m_lds[4][HID];
  const int wave = threadIdx.x >> 6, lane = threadIdx.x & 63;
  const int eid = blockIdx.x * 4 + wave;    // E divisible by 4
  const int src = __builtin_amdgcn_readfirstlane(srcs[eid]);
  const int dst = __builtin_amdgcn_readfirstlane(dsts[eid]);

  const float dx = vbuf[src * 3 + 0] - vbuf[dst * 3 + 0];
  const float dy = vbuf[src * 3 + 1] - vbuf[dst * 3 + 1];
  const float dz = vbuf[src * 3 + 2] - vbuf[dst * 3 + 2];
  const float dist = sqrtf(dx * dx + dy * dy + dz * dz + EPS_D);
  const float cw = (dist < CUTOFF)
                       ? 0.5f * (__cosf((float)M_PI / CUTOFF * dist) + 1.0f)
                       : 0.0f;

  const float2 e2 = reinterpret_cast<const float2*>(e_src_buf + (size_t)eid * EDIM)[lane];
  reinterpret_cast<float2*>(e_lds[wave])[lane] = e2;
  const float ea = ead[eid];

  float acc = Sa[(size_t)src * HID + lane] + Sb[(size_t)dst * HID + lane]
            + dist * w1d[lane] + ea * w1a[lane];
  __syncthreads();
#pragma unroll 8
  for (int k = 0; k < EDIM; ++k)
    acc += e_lds[wave][k] * W1e[k * HID + lane];
  const float h1 = silu_f(acc);

  m_lds[wave][lane] = h1;
  __syncthreads();
  float acc2 = be2_[lane];
#pragma unroll 8
  for (int k = 0; k < HID; ++k)
    acc2 += m_lds[wave][k] * We2_[k * HID + lane];
  const float m = silu_f(acc2) * cw;

  __syncthreads();  // protect m_lds overwrite (WAR across the block's waves share nothing, belt+braces)
  m_lds[wave][lane] = m;
  __syncthreads();

  float oA = beo_[lane] + e_lds[wave][lane];
  float oB = beo_[lane + 64] + e_lds[wave][lane + 64];
#pragma unroll 8
  for (int k = 0; k < HID; ++k) {
    const float mk = m_lds[wave][k];
    oA += mk * Weo_[k * EDIM + lane];
    oB += mk * Weo_[k * EDIM + lane + 64];
  }
  e_dst_buf[(size_t)eid * EDIM + lane] = oA;
  e_dst_buf[(size_t)eid * EDIM + lane + 64] = oB;

  // wv = dot(m, Wv) + bv
  float t = m * Wv_[lane];
#pragma unroll
  for (int off = 32; off > 0; off >>= 1) t += __shfl_xor(t, off);
  const float wv = t + bv_[0];

  if (lane < 3) {
    const float r = (lane == 0) ? dx : ((lane == 1) ? dy : dz);
    atomicAdd(&v_acc[(size_t)dst * 3 + lane], r * wv);
  }
  atomicAdd(&agg[(size_t)dst * HID + lane], m);
}

// one wave per node: v update, s update; re-zero v_acc/agg for next depth
__global__ __launch_bounds__(256) void k_node_upd(
    const float* __restrict__ s_src, float* __restrict__ s_dst,
    const float* __restrict__ v_src, float* __restrict__ v_dst,
    float* __restrict__ v_acc, float* __restrict__ agg,
    const float* __restrict__ deginv,
    const float* __restrict__ Ws1_, const float* __restrict__ bs1_,
    const float* __restrict__ Ws2_, const float* __restrict__ bs2_) {
  __shared__ float s_lds[4][SDIM];
  __shared__ float a_lds[4][HID];
  const int wave = threadIdx.x >> 6, lane = threadIdx.x & 63;
  const int node = blockIdx.x * 4 + wave;
  const float di = deginv[node];

  if (lane < 3) {
    v_dst[(size_t)node * 3 + lane] = v_src[(size_t)node * 3 + lane]
                                   + v_acc[(size_t)node * 3 + lane] * di;
    v_acc[(size_t)node * 3 + lane] = 0.0f;
  }

  const float2 s2 = reinterpret_cast<const float2*>(s_src + (size_t)node * SDIM)[lane];
  reinterpret_cast<float2*>(s_lds[wave])[lane] = s2;
  const float aj = agg[(size_t)node * HID + lane] * di;
  agg[(size_t)node * HID + lane] = 0.0f;
  a_lds[wave][lane] = aj;
  __syncthreads();

  float acc = bs1_[lane];
#pragma unroll 8
  for (int k = 0; k < SDIM; ++k)
    acc += s_lds[wave][k] * Ws1_[k * HID + lane];
#pragma unroll 8
  for (int k = 0; k < HID; ++k)
    acc += a_lds[wave][k] * Ws1_[(SDIM + k) * HID + lane];
  const float h = silu_f(acc);

  __syncthreads();
  a_lds[wave][lane] = h;
  __syncthreads();

  float o1 = bs2_[lane] + s_lds[wave][lane];
  float o2 = bs2_[lane + 64] + s_lds[wave][lane + 64];
#pragma unroll 8
  for (int k = 0; k < HID; ++k) {
    const float hk = a_lds[wave][k];
    o1 += hk * Ws2_[k * SDIM + lane];
    o2 += hk * Ws2_[k * SDIM + lane + 64];
  }
  s_dst[(size_t)node * SDIM + lane] = o1;
  s_dst[(size_t)node * SDIM + lane + 64] = o2;
}

extern "C" void kernel_launch(void* const* d_in, const int* in_sizes, int n_in,
                              void* d_out, int out_size, void* d_ws, size_t ws_size,
                              hipStream_t stream) {
  const float* s_in = (const float*)d_in[0];
  const float* v_in = (const float*)d_in[1];
  const float* e_in = (const float*)d_in[2];
  const int*   eidx = (const int*)d_in[3];
  const float* ead  = (const float*)d_in[4];
  // d_in[5] = ea_r (unused), d_in[6] = batch (unused)
  const float* We1 = (const float*)d_in[7];
  const float* be1 = (const float*)d_in[8];
  const float* We2 = (const float*)d_in[9];
  const float* be2 = (const float*)d_in[10];
  const float* Weo = (const float*)d_in[11];
  const float* beo = (const float*)d_in[12];
  const float* Wv  = (const float*)d_in[13];
  const float* bv  = (const float*)d_in[14];
  const float* Ws1 = (const float*)d_in[15];
  const float* bs1 = (const float*)d_in[16];
  const float* Ws2 = (const float*)d_in[17];
  const float* bs2 = (const float*)d_in[18];

  float* out_s = (float*)d_out;                       // [N,128]
  float* out_v = out_s + (size_t)N_NODES * SDIM;      // [N,3]
  float* out_e = out_v + (size_t)N_NODES * 3;         // [E,128]

  float* ws     = (float*)d_ws;
  float* deginv = ws;                                 // N
  float* v_acc  = deginv + N_NODES;                   // 3N
  float* agg    = v_acc + (size_t)3 * N_NODES;        // 64N
  float* Sa     = agg + (size_t)64 * N_NODES;         // 64N
  float* Sb     = Sa + (size_t)64 * N_NODES;          // 64N

  const int* srcs = eidx;
  const int* dsts = eidx + N_EDGES;

  // zero deginv + v_acc + agg (contiguous 68N floats)
  hipLaunchKernelGGL(k_zero, dim3(512), dim3(256), 0, stream,
                     deginv, (1 + 3 + 64) * N_NODES);
  hipLaunchKernelGGL(k_deg_count, dim3((N_EDGES + 255) / 256), dim3(256), 0, stream,
                     dsts, deginv, N_EDGES);
  hipLaunchKernelGGL(k_deg_inv, dim3((N_NODES + 255) / 256), dim3(256), 0, stream,
                     deginv, N_NODES);

  for (int i = 0; i < DEPTH; ++i) {
    const float* W1i = We1 + (size_t)i * MSG_IN * HID;
    hipLaunchKernelGGL(k_node_pre, dim3(N_NODES / 4), dim3(256), 0, stream,
                       (i == 0) ? s_in : out_s, W1i, be1 + i * HID, Sa, Sb);
    hipLaunchKernelGGL(k_edge, dim3(N_EDGES / 4), dim3(256), 0, stream,
                       (i == 0) ? e_in : out_e, out_e,
                       (i == 0) ? v_in : out_v,
                       Sa, Sb, srcs, dsts, ead,
                       W1i + 256 * HID, W1i + 384 * HID, W1i + 385 * HID,
                       We2 + (size_t)i * HID * HID, be2 + i * HID,
                       Weo + (size_t)i * HID * EDIM, beo + i * EDIM,
                       Wv + i * HID, bv + i,
                       v_acc, agg);
    hipLaunchKernelGGL(k_node_upd, dim3(N_NODES / 4), dim3(256), 0, stream,
                       (i == 0) ? s_in : out_s, out_s,
                       (i == 0) ? v_in : out_v, out_v,
                       v_acc, agg, deginv,
                       Ws1 + (size_t)i * SCAL_IN * HID, bs1 + i * HID,
                       Ws2 + (size_t)i * HID * SDIM, bs2 + i * SDIM);
  }
}

// Round 2
// 3126.065 us; speedup vs baseline: 1.8696x; 1.8696x over previous
//
#include <hip/hip_runtime.h>
#include <math.h>

#define N_NODES 40000
#define N_EDGES 512000
#define SDIM 128
#define EDIM 128
#define HID 64
#define DEPTH 4
#define MSG_IN 386   // 2*SDIM + EDIM + 2
#define SCAL_IN 192  // SDIM + HID
#define CUTOFF 5.0f
#define EPS_D 1e-6f

#define EB 4                 // edges per wave-iteration
#define EDGE_BLOCKS 256      // 1 block per CU, grid-resident
#define EDGE_THREADS 1024    // 16 waves
#define TOTAL_WAVES (EDGE_BLOCKS * 16)
#define N_TILES (N_EDGES / EB)

__device__ __forceinline__ float silu_f(float x) { return x / (1.0f + __expf(-x)); }

__global__ __launch_bounds__(256) void k_zero(float* __restrict__ p, int n) {
  int i = blockIdx.x * 256 + threadIdx.x;
  int stride = gridDim.x * 256;
  for (; i < n; i += stride) p[i] = 0.0f;
}

__global__ __launch_bounds__(256) void k_deg_count(const int* __restrict__ dst,
                                                   float* __restrict__ deg, int ne) {
  int i = blockIdx.x * 256 + threadIdx.x;
  if (i < ne) atomicAdd(&deg[dst[i]], 1.0f);
}

__global__ __launch_bounds__(256) void k_deg_inv(float* __restrict__ deg, int n) {
  int i = blockIdx.x * 256 + threadIdx.x;
  if (i < n) deg[i] = 1.0f / fmaxf(deg[i], 1.0f);
}

// Sa = s @ We1[rows 0:128] + be1 ; Sb = s @ We1[rows 128:256]
__global__ __launch_bounds__(256) void k_node_pre(
    const float* __restrict__ s, const float* __restrict__ W1,
    const float* __restrict__ be1_, float* __restrict__ Sa, float* __restrict__ Sb) {
  __shared__ float s_lds[4][SDIM];
  const int wave = threadIdx.x >> 6, lane = threadIdx.x & 63;
  const int node = blockIdx.x * 4 + wave;
  const float2 s2 = reinterpret_cast<const float2*>(s + (size_t)node * SDIM)[lane];
  reinterpret_cast<float2*>(s_lds[wave])[lane] = s2;
  __syncthreads();
  float a = be1_[lane], b = 0.0f;
#pragma unroll 8
  for (int k = 0; k < SDIM; ++k) {
    const float sk = s_lds[wave][k];
    a += sk * W1[k * HID + lane];
    b += sk * W1[(SDIM + k) * HID + lane];
  }
  Sa[(size_t)node * HID + lane] = a;
  Sb[(size_t)node * HID + lane] = b;
}

// Fused edge kernel: all weights LDS-resident, 4-edge register blocking per wave.
// LDS layout (dwords):
//   [0,8192)      W1t  : W1e^T swizzled, col c in [c*128 .. c*128+127]
//   [8192,12288)  We2t : We2^T swizzled, col c in [c*64 ...]
//   [12288,20480) WeoT : Weo^T swizzled, col c (0..127) in [c*64 ...]
//   [20480,28672) e tiles: per wave 512 dwords = [EB][128]
//   [28672,32768) m tiles: per wave 256 dwords = [EB][64]
__global__ __launch_bounds__(EDGE_THREADS, 4) void k_edge_fused(
    float* __restrict__ e_buf,            // in/out (per-row in-place)
    const float* __restrict__ vbuf,
    const float* __restrict__ Sa, const float* __restrict__ Sb,
    const int* __restrict__ srcs, const int* __restrict__ dsts,
    const float* __restrict__ ead,
    const float* __restrict__ W1e,        // [128][64] rows 256..383 of We1[i]
    const float* __restrict__ w1d,        // row 384
    const float* __restrict__ w1a,        // row 385
    const float* __restrict__ We2_, const float* __restrict__ be2_,
    const float* __restrict__ Weo_, const float* __restrict__ beo_,
    const float* __restrict__ Wv_, const float* __restrict__ bv_,
    float* __restrict__ v_acc, float* __restrict__ agg) {
  __shared__ float lds[32768];   // 128 KiB
  const int tid = threadIdx.x;
  const int lane = tid & 63;
  const int wv_id = tid >> 6;

  // ---- stage weights (transposed + XOR-swizzled along k within 16B groups) ----
#pragma unroll 2
  for (int idx = tid; idx < 128 * 64; idx += EDGE_THREADS) {
    const int k = idx >> 6, c = idx & 63;   // W1e[k][c]
    lds[c * 128 + ((((k >> 2) ^ (c & 7)) << 2) | (k & 3))] = W1e[idx];
  }
  for (int idx = tid; idx < 64 * 64; idx += EDGE_THREADS) {
    const int k = idx >> 6, c = idx & 63;
    lds[8192 + c * 64 + ((((k >> 2) ^ (c & 7)) << 2) | (k & 3))] = We2_[idx];
  }
#pragma unroll 2
  for (int idx = tid; idx < 64 * 128; idx += EDGE_THREADS) {
    const int k = idx >> 7, c = idx & 127;  // Weo[k][c]
    lds[12288 + c * 64 + ((((k >> 2) ^ (c & 7)) << 2) | (k & 3))] = Weo_[idx];
  }
  __syncthreads();

  // per-lane constants
  const float w1d_l = w1d[lane];
  const float w1a_l = w1a[lane];
  const float be2_l = be2_[lane];
  const float beoA  = beo_[lane];
  const float beoB  = beo_[lane + 64];
  const float wv_l  = Wv_[lane];
  const float bv0   = bv_[0];
  const int sw = lane & 7;

  float* eW = lds + 20480 + wv_id * (EB * 128);  // [EB][128]
  float* mW = lds + 28672 + wv_id * (EB * 64);   // [EB][64]
  const float* W1t  = lds;
  const float* We2t = lds + 8192;
  const float* WeoT = lds + 12288;

  const int wave_g = blockIdx.x * 16 + wv_id;

  for (int t = wave_g; t < N_TILES; t += TOTAL_WAVES) {
    const int e0 = t * EB;
    int srcj[EB], dstj[EB];
    float dxj[EB], dyj[EB], dzj[EB], cwj[EB];
    float acc[EB];

#pragma unroll
    for (int j = 0; j < EB; ++j) {
      const int eid = e0 + j;
      const int src = __builtin_amdgcn_readfirstlane(srcs[eid]);
      const int dst = __builtin_amdgcn_readfirstlane(dsts[eid]);
      srcj[j] = src; dstj[j] = dst;
      const float dx = vbuf[src * 3 + 0] - vbuf[dst * 3 + 0];
      const float dy = vbuf[src * 3 + 1] - vbuf[dst * 3 + 1];
      const float dz = vbuf[src * 3 + 2] - vbuf[dst * 3 + 2];
      dxj[j] = dx; dyj[j] = dy; dzj[j] = dz;
      const float dist = sqrtf(dx * dx + dy * dy + dz * dz + EPS_D);
      cwj[j] = (dist < CUTOFF)
                   ? 0.5f * (__cosf((float)M_PI / CUTOFF * dist) + 1.0f)
                   : 0.0f;
      // stage e row into wave-private LDS
      const float2 ev = reinterpret_cast<const float2*>(e_buf + (size_t)eid * EDIM)[lane];
      reinterpret_cast<float2*>(eW + j * 128)[lane] = ev;
      acc[j] = Sa[(size_t)src * HID + lane] + Sb[(size_t)dst * HID + lane]
             + dist * w1d_l + ead[eid] * w1a_l;
    }

    // ---- G1: acc += e @ W1e  (K=128) ----
#pragma unroll 4
    for (int k4 = 0; k4 < 32; ++k4) {
      const float4 w4 = *reinterpret_cast<const float4*>(&W1t[lane * 128 + ((k4 ^ sw) << 2)]);
#pragma unroll
      for (int j = 0; j < EB; ++j) {
        const float4 e4 = *reinterpret_cast<const float4*>(&eW[j * 128 + (k4 << 2)]);
        acc[j] = fmaf(w4.x, e4.x, acc[j]);
        acc[j] = fmaf(w4.y, e4.y, acc[j]);
        acc[j] = fmaf(w4.z, e4.z, acc[j]);
        acc[j] = fmaf(w4.w, e4.w, acc[j]);
      }
    }
#pragma unroll
    for (int j = 0; j < EB; ++j) mW[j * 64 + lane] = silu_f(acc[j]);

    // ---- G2: acc2 = h1 @ We2 (K=64) ----
    float acc2[EB];
#pragma unroll
    for (int j = 0; j < EB; ++j) acc2[j] = be2_l;
#pragma unroll 4
    for (int k4 = 0; k4 < 16; ++k4) {
      const float4 w4 = *reinterpret_cast<const float4*>(&We2t[lane * 64 + ((k4 ^ sw) << 2)]);
#pragma unroll
      for (int j = 0; j < EB; ++j) {
        const float4 h4 = *reinterpret_cast<const float4*>(&mW[j * 64 + (k4 << 2)]);
        acc2[j] = fmaf(w4.x, h4.x, acc2[j]);
        acc2[j] = fmaf(w4.y, h4.y, acc2[j]);
        acc2[j] = fmaf(w4.z, h4.z, acc2[j]);
        acc2[j] = fmaf(w4.w, h4.w, acc2[j]);
      }
    }
    float mj[EB];
#pragma unroll
    for (int j = 0; j < EB; ++j) mj[j] = silu_f(acc2[j]) * cwj[j];
#pragma unroll
    for (int j = 0; j < EB; ++j) mW[j * 64 + lane] = mj[j];

    // ---- GEMMo: e += m @ Weo (K=64, 128 cols -> lane, lane+64) ----
    float oA[EB], oB[EB];
#pragma unroll
    for (int j = 0; j < EB; ++j) {
      oA[j] = beoA + eW[j * 128 + lane];
      oB[j] = beoB + eW[j * 128 + 64 + lane];
    }
#pragma unroll 4
    for (int k4 = 0; k4 < 16; ++k4) {
      const float4 wA = *reinterpret_cast<const float4*>(&WeoT[lane * 64 + ((k4 ^ sw) << 2)]);
      const float4 wB = *reinterpret_cast<const float4*>(&WeoT[(lane + 64) * 64 + ((k4 ^ sw) << 2)]);
#pragma unroll
      for (int j = 0; j < EB; ++j) {
        const float4 m4 = *reinterpret_cast<const float4*>(&mW[j * 64 + (k4 << 2)]);
        oA[j] = fmaf(m4.x, wA.x, oA[j]); oB[j] = fmaf(m4.x, wB.x, oB[j]);
        oA[j] = fmaf(m4.y, wA.y, oA[j]); oB[j] = fmaf(m4.y, wB.y, oB[j]);
        oA[j] = fmaf(m4.z, wA.z, oA[j]); oB[j] = fmaf(m4.z, wB.z, oB[j]);
        oA[j] = fmaf(m4.w, wA.w, oA[j]); oB[j] = fmaf(m4.w, wB.w, oB[j]);
      }
    }

    // ---- epilogue: e store, wv reduce, atomics ----
#pragma unroll
    for (int j = 0; j < EB; ++j) {
      const int eid = e0 + j;
      e_buf[(size_t)eid * EDIM + lane] = oA[j];
      e_buf[(size_t)eid * EDIM + 64 + lane] = oB[j];
      float tsum = mj[j] * wv_l;
#pragma unroll
      for (int off = 32; off > 0; off >>= 1) tsum += __shfl_xor(tsum, off);
      const float wvj = tsum + bv0;
      if (lane < 3) {
        const float r = (lane == 0) ? dxj[j] : ((lane == 1) ? dyj[j] : dzj[j]);
        atomicAdd(&v_acc[(size_t)dstj[j] * 3 + lane], r * wvj);
      }
      atomicAdd(&agg[(size_t)dstj[j] * HID + lane], mj[j]);
    }
  }
}

// one wave per node: v update, s update; re-zero v_acc/agg for next depth
__global__ __launch_bounds__(256) void k_node_upd(
    const float* __restrict__ s_src, float* __restrict__ s_dst,
    const float* __restrict__ v_src, float* __restrict__ v_dst,
    float* __restrict__ v_acc, float* __restrict__ agg,
    const float* __restrict__ deginv,
    const float* __restrict__ Ws1_, const float* __restrict__ bs1_,
    const float* __restrict__ Ws2_, const float* __restrict__ bs2_) {
  __shared__ float s_lds[4][SDIM];
  __shared__ float a_lds[4][HID];
  const int wave = threadIdx.x >> 6, lane = threadIdx.x & 63;
  const int node = blockIdx.x * 4 + wave;
  const float di = deginv[node];

  if (lane < 3) {
    v_dst[(size_t)node * 3 + lane] = v_src[(size_t)node * 3 + lane]
                                   + v_acc[(size_t)node * 3 + lane] * di;
    v_acc[(size_t)node * 3 + lane] = 0.0f;
  }

  const float2 s2 = reinterpret_cast<const float2*>(s_src + (size_t)node * SDIM)[lane];
  reinterpret_cast<float2*>(s_lds[wave])[lane] = s2;
  const float aj = agg[(size_t)node * HID + lane] * di;
  agg[(size_t)node * HID + lane] = 0.0f;
  a_lds[wave][lane] = aj;
  __syncthreads();

  float acc = bs1_[lane];
#pragma unroll 8
  for (int k = 0; k < SDIM; ++k)
    acc += s_lds[wave][k] * Ws1_[k * HID + lane];
#pragma unroll 8
  for (int k = 0; k < HID; ++k)
    acc += a_lds[wave][k] * Ws1_[(SDIM + k) * HID + lane];
  const float h = silu_f(acc);

  __syncthreads();
  a_lds[wave][lane] = h;
  __syncthreads();

  float o1 = bs2_[lane] + s_lds[wave][lane];
  float o2 = bs2_[lane + 64] + s_lds[wave][lane + 64];
#pragma unroll 8
  for (int k = 0; k < HID; ++k) {
    const float hk = a_lds[wave][k];
    o1 += hk * Ws2_[k * SDIM + lane];
    o2 += hk * Ws2_[k * SDIM + lane + 64];
  }
  s_dst[(size_t)node * SDIM + lane] = o1;
  s_dst[(size_t)node * SDIM + lane + 64] = o2;
}

extern "C" void kernel_launch(void* const* d_in, const int* in_sizes, int n_in,
                              void* d_out, int out_size, void* d_ws, size_t ws_size,
                              hipStream_t stream) {
  const float* s_in = (const float*)d_in[0];
  const float* v_in = (const float*)d_in[1];
  const float* e_in = (const float*)d_in[2];
  const int*   eidx = (const int*)d_in[3];
  const float* ead  = (const float*)d_in[4];
  const float* We1 = (const float*)d_in[7];
  const float* be1 = (const float*)d_in[8];
  const float* We2 = (const float*)d_in[9];
  const float* be2 = (const float*)d_in[10];
  const float* Weo = (const float*)d_in[11];
  const float* beo = (const float*)d_in[12];
  const float* Wv  = (const float*)d_in[13];
  const float* bv  = (const float*)d_in[14];
  const float* Ws1 = (const float*)d_in[15];
  const float* bs1 = (const float*)d_in[16];
  const float* Ws2 = (const float*)d_in[17];
  const float* bs2 = (const float*)d_in[18];

  float* out_s = (float*)d_out;                       // [N,128]
  float* out_v = out_s + (size_t)N_NODES * SDIM;      // [N,3]
  float* out_e = out_v + (size_t)N_NODES * 3;         // [E,128]

  float* ws     = (float*)d_ws;
  float* deginv = ws;                                 // N
  float* v_acc  = deginv + N_NODES;                   // 3N
  float* agg    = v_acc + (size_t)3 * N_NODES;        // 64N
  float* Sa     = agg + (size_t)64 * N_NODES;         // 64N
  float* Sb     = Sa + (size_t)64 * N_NODES;          // 64N

  const int* srcs = eidx;
  const int* dsts = eidx + N_EDGES;

  hipLaunchKernelGGL(k_zero, dim3(512), dim3(256), 0, stream,
                     deginv, (1 + 3 + 64) * N_NODES);
  hipLaunchKernelGGL(k_deg_count, dim3((N_EDGES + 255) / 256), dim3(256), 0, stream,
                     dsts, deginv, N_EDGES);
  hipLaunchKernelGGL(k_deg_inv, dim3((N_NODES + 255) / 256), dim3(256), 0, stream,
                     deginv, N_NODES);

  for (int i = 0; i < DEPTH; ++i) {
    const float* W1i = We1 + (size_t)i * MSG_IN * HID;
    hipLaunchKernelGGL(k_node_pre, dim3(N_NODES / 4), dim3(256), 0, stream,
                       (i == 0) ? s_in : out_s, W1i, be1 + i * HID, Sa, Sb);
    if (i == 0) {
      // seed out_e with e_in via the fused kernel reading e_in? No: copy rows once.
      hipMemcpyAsync(out_e, e_in, (size_t)N_EDGES * EDIM * sizeof(float),
                     hipMemcpyDeviceToDevice, stream);
    }
    hipLaunchKernelGGL(k_edge_fused, dim3(EDGE_BLOCKS), dim3(EDGE_THREADS), 0, stream,
                       out_e,
                       (i == 0) ? v_in : out_v,
                       Sa, Sb, srcs, dsts, ead,
                       W1i + 256 * HID, W1i + 384 * HID, W1i + 385 * HID,
                       We2 + (size_t)i * HID * HID, be2 + i * HID,
                       Weo + (size_t)i * HID * EDIM, beo + i * EDIM,
                       Wv + i * HID, bv + i,
                       v_acc, agg);
    hipLaunchKernelGGL(k_node_upd, dim3(N_NODES / 4), dim3(256), 0, stream,
                       (i == 0) ? s_in : out_s, out_s,
                       (i == 0) ? v_in : out_v, out_v,
                       v_acc, agg, deginv,
                       Ws1 + (size_t)i * SCAL_IN * HID, bs1 + i * HID,
                       Ws2 + (size_t)i * HID * SDIM, bs2 + i * SDIM);
  }
}

// Round 3
// 1577.512 us; speedup vs baseline: 3.7049x; 1.9816x over previous
//
#include <hip/hip_runtime.h>
#include <math.h>

#define N_NODES 40000
#define N_EDGES 512000
#define SDIM 128
#define EDIM 128
#define HID 64
#define DEPTH 4
#define MSG_IN 386   // 2*SDIM + EDIM + 2
#define SCAL_IN 192  // SDIM + HID
#define CUTOFF 5.0f
#define EPS_D 1e-6f

#define TILE_M 16
#define EW 8                  // waves per block
#define ETHREADS 512
#define EBLOCKS 256
#define TWAVES (EBLOCKS * EW)
#define NTILES (N_EDGES / TILE_M)   // 32000

typedef __attribute__((ext_vector_type(8))) short short8;
typedef __attribute__((ext_vector_type(4))) float f32x4;

__device__ __forceinline__ float silu_f(float x) { return x / (1.0f + __expf(-x)); }

__device__ __forceinline__ unsigned short f2b(float x) {
  union { float f; unsigned int u; } v; v.f = x;
  unsigned int r = v.u + 0x7FFFu + ((v.u >> 16) & 1u);
  return (unsigned short)(r >> 16);
}

__global__ __launch_bounds__(256) void k_zero(float* __restrict__ p, int n) {
  int i = blockIdx.x * 256 + threadIdx.x;
  int stride = gridDim.x * 256;
  for (; i < n; i += stride) p[i] = 0.0f;
}

__global__ __launch_bounds__(256) void k_deg_count(const int* __restrict__ dst,
                                                   float* __restrict__ deg, int ne) {
  int i = blockIdx.x * 256 + threadIdx.x;
  if (i < ne) atomicAdd(&deg[dst[i]], 1.0f);
}

__global__ __launch_bounds__(256) void k_deg_inv(float* __restrict__ deg, int n) {
  int i = blockIdx.x * 256 + threadIdx.x;
  if (i < n) deg[i] = 1.0f / fmaxf(deg[i], 1.0f);
}

// Sa = s @ We1[rows 0:128] + be1 ; Sb = s @ We1[rows 128:256]
__global__ __launch_bounds__(256) void k_node_pre(
    const float* __restrict__ s, const float* __restrict__ W1,
    const float* __restrict__ be1_, float* __restrict__ Sa, float* __restrict__ Sb) {
  __shared__ float s_lds[4][SDIM];
  const int wave = threadIdx.x >> 6, lane = threadIdx.x & 63;
  const int node = blockIdx.x * 4 + wave;
  const float2 s2 = reinterpret_cast<const float2*>(s + (size_t)node * SDIM)[lane];
  reinterpret_cast<float2*>(s_lds[wave])[lane] = s2;
  __syncthreads();
  float a = be1_[lane], b = 0.0f;
#pragma unroll 8
  for (int k = 0; k < SDIM; ++k) {
    const float sk = s_lds[wave][k];
    a += sk * W1[k * HID + lane];
    b += sk * W1[(SDIM + k) * HID + lane];
  }
  Sa[(size_t)node * HID + lane] = a;
  Sb[(size_t)node * HID + lane] = b;
}

// MFMA edge kernel. One wave = one 16-edge tile (grid-stride).
// Fragment layouts (mfma_f32_16x16x32_bf16):
//   A[m][k]: m=lane&15, k=(lane>>4)*8+i   (8 bf16 = 1 ds_read_b128)
//   B[k][n]: n=lane&15, k=(lane>>4)*8+i
//   D[m][n]: n=lane&15, m=(lane>>4)*4+reg (guide-verified)
// LDS strides: all fragment rows are (K+8) bf16 => row stride ≡ 4 dwords mod 32,
// so each consecutive-8-lane phase of a b128 read hits all 32 banks.
__global__ __launch_bounds__(ETHREADS, 2) void k_edge_mfma(
    const float* __restrict__ e_src, float* __restrict__ e_dst,
    const float* __restrict__ vbuf,
    const float* __restrict__ Sa, const float* __restrict__ Sb,
    const int* __restrict__ srcs, const int* __restrict__ dsts,
    const float* __restrict__ ead,
    const float* __restrict__ W1e,   // [128][64] rows 256..383 of We1[i]
    const float* __restrict__ w1d, const float* __restrict__ w1a,
    const float* __restrict__ We2_, const float* __restrict__ be2_,
    const float* __restrict__ Weo_, const float* __restrict__ beo_,
    const float* __restrict__ Wv_, const float* __restrict__ bv_,
    float* __restrict__ v_acc, float* __restrict__ agg) {
  __shared__ __align__(16) unsigned short W1t[64 * 136];    // [n][k], K=128+8
  __shared__ __align__(16) unsigned short We2t[64 * 72];    // [n][k], K=64+8
  __shared__ __align__(16) unsigned short WeoT[128 * 72];   // [n][k], K=64+8
  __shared__ __align__(16) unsigned short eT[EW][TILE_M * 136];
  __shared__ __align__(16) float hm[EW][TILE_M * 68];
  __shared__ __align__(16) float sbuf[EW][128];

  const int tid = threadIdx.x;
  const int lane = tid & 63;
  const int w = tid >> 6;
  const int c = lane & 15;   // A-row / B-col / D-col
  const int g = lane >> 4;   // k-group / D-row-group

  // ---- stage weights to LDS as bf16, col-major [n][k] ----
  for (int idx = tid; idx < 128 * 64; idx += ETHREADS) {
    const int k = idx >> 6, n = idx & 63;
    W1t[n * 136 + k] = f2b(W1e[idx]);
  }
  for (int idx = tid; idx < 64 * 64; idx += ETHREADS) {
    const int k = idx >> 6, n = idx & 63;
    We2t[n * 72 + k] = f2b(We2_[idx]);
  }
  for (int idx = tid; idx < 64 * 128; idx += ETHREADS) {
    const int k = idx >> 7, n = idx & 127;
    WeoT[n * 72 + k] = f2b(Weo_[idx]);
  }
  __syncthreads();

  float w1d_l[4], w1a_l[4], be2_l[4], Wv_l[4], beo_l[8];
#pragma unroll
  for (int nt = 0; nt < 4; ++nt) {
    w1d_l[nt] = w1d[nt * 16 + c];
    w1a_l[nt] = w1a[nt * 16 + c];
    be2_l[nt] = be2_[nt * 16 + c];
    Wv_l[nt]  = Wv_[nt * 16 + c];
  }
#pragma unroll
  for (int nt = 0; nt < 8; ++nt) beo_l[nt] = beo_[nt * 16 + c];
  const float bv0 = bv_[0];

  unsigned short* eTw = eT[w];
  float* hmw = hm[w];
  float* sb = sbuf[w];
  int* sbi = (int*)sb;

  for (int t = blockIdx.x * EW + w; t < NTILES; t += TWAVES) {
    const int e0 = t * TILE_M;

    // ---- prologue: per-edge scalars (lanes 0..15) ----
    if (lane < 16) {
      const int eid = e0 + lane;
      const int s_ = srcs[eid], d_ = dsts[eid];
      const float dx = vbuf[s_ * 3 + 0] - vbuf[d_ * 3 + 0];
      const float dy = vbuf[s_ * 3 + 1] - vbuf[d_ * 3 + 1];
      const float dz = vbuf[s_ * 3 + 2] - vbuf[d_ * 3 + 2];
      const float dist = sqrtf(dx * dx + dy * dy + dz * dz + EPS_D);
      const float cwv = (dist < CUTOFF)
                            ? 0.5f * (__cosf((float)M_PI / CUTOFF * dist) + 1.0f)
                            : 0.0f;
      sb[lane] = dist; sb[16 + lane] = cwv; sb[32 + lane] = ead[eid];
      sb[48 + lane] = dx; sb[64 + lane] = dy; sb[80 + lane] = dz;
      sbi[96 + lane] = s_; sbi[112 + lane] = d_;
    }

    // ---- stage e tile (fp32 global -> bf16 LDS, A-layout rows) ----
    {
      const f32x4* ebase = (const f32x4*)(e_src + (size_t)e0 * EDIM);
#pragma unroll
      for (int i = 0; i < 4; ++i) {
        const int f = i * 128 + lane * 2;  // float4 units; 32 per row
        const f32x4 a = ebase[f];
        const f32x4 b = ebase[f + 1];
        const int row = i * 4 + g;
        union { unsigned short u[8]; short8 s8; } pk;
        pk.u[0] = f2b(a[0]); pk.u[1] = f2b(a[1]); pk.u[2] = f2b(a[2]); pk.u[3] = f2b(a[3]);
        pk.u[4] = f2b(b[0]); pk.u[5] = f2b(b[1]); pk.u[6] = f2b(b[2]); pk.u[7] = f2b(b[3]);
        *(short8*)&eTw[row * 136 + c * 8] = pk.s8;
      }
    }

    // per-D-row scalars
    int src_r[4], dst_r[4];
    float dist_r[4], cw_r[4], ea_r[4];
#pragma unroll
    for (int r = 0; r < 4; ++r) {
      const int row = g * 4 + r;
      dist_r[r] = sb[row]; cw_r[r] = sb[16 + row]; ea_r[r] = sb[32 + row];
      src_r[r] = sbi[96 + row]; dst_r[r] = sbi[112 + row];
    }

    // ---- G1: acc = Sa[src]+Sb[dst]+dist*w1d+ea*w1a + e @ W1e ----
    f32x4 acc[4];
#pragma unroll
    for (int nt = 0; nt < 4; ++nt)
#pragma unroll
      for (int r = 0; r < 4; ++r)
        acc[nt][r] = Sa[(size_t)src_r[r] * HID + nt * 16 + c]
                   + Sb[(size_t)dst_r[r] * HID + nt * 16 + c]
                   + dist_r[r] * w1d_l[nt] + ea_r[r] * w1a_l[nt];
#pragma unroll
    for (int kc = 0; kc < 4; ++kc) {
      const short8 af = *(const short8*)&eTw[c * 136 + kc * 32 + g * 8];
#pragma unroll
      for (int nt = 0; nt < 4; ++nt) {
        const short8 bf = *(const short8*)&W1t[(nt * 16 + c) * 136 + kc * 32 + g * 8];
        acc[nt] = __builtin_amdgcn_mfma_f32_16x16x32_bf16(af, bf, acc[nt], 0, 0, 0);
      }
    }
    // h1 = silu(acc) -> hm (fp32)
#pragma unroll
    for (int nt = 0; nt < 4; ++nt)
#pragma unroll
      for (int r = 0; r < 4; ++r)
        hmw[(g * 4 + r) * 68 + nt * 16 + c] = silu_f(acc[nt][r]);

    // ---- G2: acc2 = h1 @ We2 + be2 ----
    f32x4 acc2[4];
#pragma unroll
    for (int nt = 0; nt < 4; ++nt)
      acc2[nt] = f32x4{be2_l[nt], be2_l[nt], be2_l[nt], be2_l[nt]};
#pragma unroll
    for (int kc = 0; kc < 2; ++kc) {
      const f32x4 lo = *(const f32x4*)&hmw[c * 68 + kc * 32 + g * 8];
      const f32x4 hi = *(const f32x4*)&hmw[c * 68 + kc * 32 + g * 8 + 4];
      union { unsigned short u[8]; short8 s8; } pk;
      pk.u[0] = f2b(lo[0]); pk.u[1] = f2b(lo[1]); pk.u[2] = f2b(lo[2]); pk.u[3] = f2b(lo[3]);
      pk.u[4] = f2b(hi[0]); pk.u[5] = f2b(hi[1]); pk.u[6] = f2b(hi[2]); pk.u[7] = f2b(hi[3]);
#pragma unroll
      for (int nt = 0; nt < 4; ++nt) {
        const short8 bf = *(const short8*)&We2t[(nt * 16 + c) * 72 + kc * 32 + g * 8];
        acc2[nt] = __builtin_amdgcn_mfma_f32_16x16x32_bf16(pk.s8, bf, acc2[nt], 0, 0, 0);
      }
    }
    // m = silu(acc2) * cw
    float mval[4][4];
#pragma unroll
    for (int nt = 0; nt < 4; ++nt)
#pragma unroll
      for (int r = 0; r < 4; ++r)
        mval[nt][r] = silu_f(acc2[nt][r]) * cw_r[r];

    // ---- agg atomics + wv reduction + v_acc atomics ----
    float tr[4] = {0.f, 0.f, 0.f, 0.f};
#pragma unroll
    for (int nt = 0; nt < 4; ++nt)
#pragma unroll
      for (int r = 0; r < 4; ++r) {
        tr[r] += mval[nt][r] * Wv_l[nt];
        atomicAdd(&agg[(size_t)dst_r[r] * HID + nt * 16 + c], mval[nt][r]);
      }
#pragma unroll
    for (int r = 0; r < 4; ++r) {
      float s = tr[r];
      s += __shfl_xor(s, 1); s += __shfl_xor(s, 2);
      s += __shfl_xor(s, 4); s += __shfl_xor(s, 8);
      const float wvv = s + bv0;
      if (c < 3) {
        const int row = g * 4 + r;
        atomicAdd(&v_acc[(size_t)dst_r[r] * 3 + c], sb[48 + 16 * c + row] * wvv);
      }
    }

    // m -> hm (fp32) for GEMMo A-frags
#pragma unroll
    for (int nt = 0; nt < 4; ++nt)
#pragma unroll
      for (int r = 0; r < 4; ++r)
        hmw[(g * 4 + r) * 68 + nt * 16 + c] = mval[nt][r];

    // ---- GEMMo: o = m @ Weo + beo (8 col-tiles) ----
    f32x4 oacc[8];
#pragma unroll
    for (int nt = 0; nt < 8; ++nt)
      oacc[nt] = f32x4{beo_l[nt], beo_l[nt], beo_l[nt], beo_l[nt]};
#pragma unroll
    for (int kc = 0; kc < 2; ++kc) {
      const f32x4 lo = *(const f32x4*)&hmw[c * 68 + kc * 32 + g * 8];
      const f32x4 hi = *(const f32x4*)&hmw[c * 68 + kc * 32 + g * 8 + 4];
      union { unsigned short u[8]; short8 s8; } pk;
      pk.u[0] = f2b(lo[0]); pk.u[1] = f2b(lo[1]); pk.u[2] = f2b(lo[2]); pk.u[3] = f2b(lo[3]);
      pk.u[4] = f2b(hi[0]); pk.u[5] = f2b(hi[1]); pk.u[6] = f2b(hi[2]); pk.u[7] = f2b(hi[3]);
#pragma unroll
      for (int nt = 0; nt < 8; ++nt) {
        const short8 bf = *(const short8*)&WeoT[(nt * 16 + c) * 72 + kc * 32 + g * 8];
        oacc[nt] = __builtin_amdgcn_mfma_f32_16x16x32_bf16(pk.s8, bf, oacc[nt], 0, 0, 0);
      }
    }

    // ---- output: bounce each 64-col half through LDS, add residual, store ----
#pragma unroll
    for (int h2 = 0; h2 < 2; ++h2) {
#pragma unroll
      for (int nt = 0; nt < 4; ++nt)
#pragma unroll
        for (int r = 0; r < 4; ++r)
          hmw[(g * 4 + r) * 68 + nt * 16 + c] = oacc[h2 * 4 + nt][r];
#pragma unroll
      for (int q = 0; q < 4; ++q) {
        const int row = q * 4 + g;
        const f32x4 val = *(const f32x4*)&hmw[row * 68 + c * 4];
        const size_t gi = (size_t)(e0 + row) * EDIM + h2 * 64 + c * 4;
        const f32x4 old = *(const f32x4*)&e_src[gi];
        f32x4 o = val + old;
        *(f32x4*)&e_dst[gi] = o;
      }
    }
  }
}

// one wave per node: v update, s update; re-zero v_acc/agg for next depth
__global__ __launch_bounds__(256) void k_node_upd(
    const float* __restrict__ s_src, float* __restrict__ s_dst,
    const float* __restrict__ v_src, float* __restrict__ v_dst,
    float* __restrict__ v_acc, float* __restrict__ agg,
    const float* __restrict__ deginv,
    const float* __restrict__ Ws1_, const float* __restrict__ bs1_,
    const float* __restrict__ Ws2_, const float* __restrict__ bs2_) {
  __shared__ float s_lds[4][SDIM];
  __shared__ float a_lds[4][HID];
  const int wave = threadIdx.x >> 6, lane = threadIdx.x & 63;
  const int node = blockIdx.x * 4 + wave;
  const float di = deginv[node];

  if (lane < 3) {
    v_dst[(size_t)node * 3 + lane] = v_src[(size_t)node * 3 + lane]
                                   + v_acc[(size_t)node * 3 + lane] * di;
    v_acc[(size_t)node * 3 + lane] = 0.0f;
  }

  const float2 s2 = reinterpret_cast<const float2*>(s_src + (size_t)node * SDIM)[lane];
  reinterpret_cast<float2*>(s_lds[wave])[lane] = s2;
  const float aj = agg[(size_t)node * HID + lane] * di;
  agg[(size_t)node * HID + lane] = 0.0f;
  a_lds[wave][lane] = aj;
  __syncthreads();

  float acc = bs1_[lane];
#pragma unroll 8
  for (int k = 0; k < SDIM; ++k)
    acc += s_lds[wave][k] * Ws1_[k * HID + lane];
#pragma unroll 8
  for (int k = 0; k < HID; ++k)
    acc += a_lds[wave][k] * Ws1_[(SDIM + k) * HID + lane];
  const float h = silu_f(acc);

  __syncthreads();
  a_lds[wave][lane] = h;
  __syncthreads();

  float o1 = bs2_[lane] + s_lds[wave][lane];
  float o2 = bs2_[lane + 64] + s_lds[wave][lane + 64];
#pragma unroll 8
  for (int k = 0; k < HID; ++k) {
    const float hk = a_lds[wave][k];
    o1 += hk * Ws2_[k * SDIM + lane];
    o2 += hk * Ws2_[k * SDIM + lane + 64];
  }
  s_dst[(size_t)node * SDIM + lane] = o1;
  s_dst[(size_t)node * SDIM + lane + 64] = o2;
}

extern "C" void kernel_launch(void* const* d_in, const int* in_sizes, int n_in,
                              void* d_out, int out_size, void* d_ws, size_t ws_size,
                              hipStream_t stream) {
  const float* s_in = (const float*)d_in[0];
  const float* v_in = (const float*)d_in[1];
  const float* e_in = (const float*)d_in[2];
  const int*   eidx = (const int*)d_in[3];
  const float* ead  = (const float*)d_in[4];
  const float* We1 = (const float*)d_in[7];
  const float* be1 = (const float*)d_in[8];
  const float* We2 = (const float*)d_in[9];
  const float* be2 = (const float*)d_in[10];
  const float* Weo = (const float*)d_in[11];
  const float* beo = (const float*)d_in[12];
  const float* Wv  = (const float*)d_in[13];
  const float* bv  = (const float*)d_in[14];
  const float* Ws1 = (const float*)d_in[15];
  const float* bs1 = (const float*)d_in[16];
  const float* Ws2 = (const float*)d_in[17];
  const float* bs2 = (const float*)d_in[18];

  float* out_s = (float*)d_out;                       // [N,128]
  float* out_v = out_s + (size_t)N_NODES * SDIM;      // [N,3]
  float* out_e = out_v + (size_t)N_NODES * 3;         // [E,128]

  float* ws     = (float*)d_ws;
  float* deginv = ws;                                 // N
  float* v_acc  = deginv + N_NODES;                   // 3N
  float* agg    = v_acc + (size_t)3 * N_NODES;        // 64N
  float* Sa     = agg + (size_t)64 * N_NODES;         // 64N
  float* Sb     = Sa + (size_t)64 * N_NODES;          // 64N

  const int* srcs = eidx;
  const int* dsts = eidx + N_EDGES;

  hipLaunchKernelGGL(k_zero, dim3(512), dim3(256), 0, stream,
                     deginv, (1 + 3 + 64) * N_NODES);
  hipLaunchKernelGGL(k_deg_count, dim3((N_EDGES + 255) / 256), dim3(256), 0, stream,
                     dsts, deginv, N_EDGES);
  hipLaunchKernelGGL(k_deg_inv, dim3((N_NODES + 255) / 256), dim3(256), 0, stream,
                     deginv, N_NODES);

  for (int i = 0; i < DEPTH; ++i) {
    const float* W1i = We1 + (size_t)i * MSG_IN * HID;
    hipLaunchKernelGGL(k_node_pre, dim3(N_NODES / 4), dim3(256), 0, stream,
                       (i == 0) ? s_in : out_s, W1i, be1 + i * HID, Sa, Sb);
    hipLaunchKernelGGL(k_edge_mfma, dim3(EBLOCKS), dim3(ETHREADS), 0, stream,
                       (i == 0) ? e_in : out_e, out_e,
                       (i == 0) ? v_in : out_v,
                       Sa, Sb, srcs, dsts, ead,
                       W1i + 256 * HID, W1i + 384 * HID, W1i + 385 * HID,
                       We2 + (size_t)i * HID * HID, be2 + i * HID,
                       Weo + (size_t)i * HID * EDIM, beo + i * EDIM,
                       Wv + i * HID, bv + i,
                       v_acc, agg);
    hipLaunchKernelGGL(k_node_upd, dim3(N_NODES / 4), dim3(256), 0, stream,
                       (i == 0) ? s_in : out_s, out_s,
                       (i == 0) ? v_in : out_v, out_v,
                       v_acc, agg, deginv,
                       Ws1 + (size_t)i * SCAL_IN * HID, bs1 + i * HID,
                       Ws2 + (size_t)i * HID * SDIM, bs2 + i * SDIM);
  }
}